// Round 11
// baseline (3868.660 us; speedup 1.0000x reference)
//
#include <hip/hip_runtime.h>

// 2D acoustic FD, 4 shots x 1000 steps. Temporal blocking K=8, 9 x-chunks/shot,
// full z in LDS (transposed). R11 on the R6 skeleton:
//  (1) 768 threads (12 waves, 3/SIMD) — same 38-zg layout, 5-row x-slices.
//  (2) split exchange: u(t+7) published+ingest-issued around k=8 (hidden),
//      u(t+8) exchanged synchronously at the transition (half payload).
// Wave-granular flags (R10 infra) for the early u(t+7) handshake.

#define NZ_ 150
#define NX_ 300
#define NT_ 1000
#define NS_ 4
#define NR_ 400
#define KS_ 8
#define NCH_ 9
#define NBND_ 8
#define HW_ 32               // halo width = 4*KS
#define ZW_ 168              // LDS z-stride
#define LROWS_ 98            // 32 + 34 + 32
#define BUF_ (LROWS_*ZW_)
#define THR_ 768
#define NRND_ 125
#define HELE_ 4800           // u64 per (s,bnd,dir,par): 2 fields * 32 rows * 75 zpairs
#define NB_H 10              // ceil(2400/256) — one field's slab per 256 threads

typedef float f4 __attribute__((ext_vector_type(4)));
typedef unsigned long long u64;

__device__ __forceinline__ void astore64(u64* p, u64 v) {
    __hip_atomic_store(p, v, __ATOMIC_RELAXED, __HIP_MEMORY_SCOPE_AGENT);
}
__device__ __forceinline__ int aload32(const int* p) {
    return __hip_atomic_load(p, __ATOMIC_RELAXED, __HIP_MEMORY_SCOPE_AGENT);
}
__device__ __forceinline__ void astore32(int* p, int v) {
    __hip_atomic_store(p, v, __ATOMIC_RELAXED, __HIP_MEMORY_SCOPE_AGENT);
}
__device__ __forceinline__ void ld2_issue(u64& d, const u64* p) {
    asm volatile("global_load_dwordx2 %0, %1, off sc0 sc1" : "=v"(d) : "v"(p));
}
// flags: [s][bnd][dir][wave 0..3]
__device__ __forceinline__ int* flagp(int* f, int s, int bnd, int dir, int wv) {
    return f + (((s * NBND_ + bnd) * 2 + dir) * 4 + wv);
}

__global__ __launch_bounds__(THR_) void wave_ox(
    const float* __restrict__ v_map, const float* __restrict__ s_amp,
    const int* __restrict__ s_loc, const int* __restrict__ r_loc,
    float* __restrict__ out, int* __restrict__ flagsA, int* __restrict__ flagsB,
    u64* __restrict__ halo)
{
    extern __shared__ float smem[];
    const int bi = blockIdx.x;
    const int s = bi & 3;
    const int h = bi >> 2;                       // 0..8
    const int tid = threadIdx.x;

    const int w  = 33 + (h < 3 ? 1 : 0);
    const int x0 = 33 * h + (h < 3 ? h : 3);
    const int rhi = HW_ + w;

    for (int i = tid; i < 2 * BUF_; i += THR_) smem[i] = 0.0f;

    const int zg = tid % 38;                     // 4-wide z group (R6 banking)
    const int xp = tid / 38;                     // x-slice, 5 rows each
    const bool comp = (tid < 760);               // 38*20
    const int c0 = 4 + 4 * zg;
    const int rbase = 5 * xp;

    f4 v2r[5];
#pragma unroll
    for (int i = 0; i < 5; ++i) {
        f4 vv = {0.f, 0.f, 0.f, 0.f};
        const int row = rbase + i;
        const int x = x0 - HW_ + row;
        if (comp && x >= 0 && x < NX_) {
#pragma unroll
            for (int j = 0; j < 4; ++j) {
                const int z = min(4 * zg + j, NZ_ - 1);
                const float v = v_map[z * NX_ + x] * 0.001f;
                vv[j] = v * v * 0.01f;           // (v*DT)^2 / DX^2
            }
        }
        v2r[i] = vv;
    }

    const int sz = s_loc[2 * s], sx = s_loc[2 * s + 1];
    float sS = v_map[sz * NX_ + sx] * 0.001f; sS = sS * sS;   // (v*DT)^2
    const int srow = sx - x0 + HW_;
    const int szg = sz >> 2;
    const int scol = 4 + sz;

    bool rown = false; int rrow = 0, rcol = 0;
    if (tid < NR_) {
        const int rz = r_loc[2 * tid];
        const int rx = r_loc[2 * tid + 1];
        if (rx >= x0 && rx < x0 + w) { rown = true; rrow = HW_ + rx - x0; rcol = 4 + rz; }
    }

    const int wv   = (tid & 255) >> 6;           // wave index within side, 0..3
    const bool sideL = (tid < 256);
    const bool sideR = (tid >= 256 && tid < 512);
    const int tidS = tid & 255;                  // 0..255 within side

    __syncthreads();

    for (int r = 0; r < NRND_; ++r) {
        u64 vb[NB_H];                            // f1 halo slab, carried across k=8
        for (int k = 1; k <= KS_; ++k) {
            const int tau = KS_ * r + k;
            const int ext = 4 * (KS_ - k);                     // 28..0
            const int L  = (h == 0)        ? HW_ : HW_ - ext;
            const int R  = (h == NCH_ - 1) ? rhi : rhi + ext;
            const float* cur = smem + ((tau + 1) & 1) * BUF_;
            float*       nxt = smem + (tau & 1) * BUF_;

            if (comp && rbase < R && rbase + 5 > L) {
                f4 W[9];
#pragma unroll
                for (int q = 0; q < 8; ++q) {
                    int rr = rbase - 4 + q; rr = rr < 0 ? 0 : rr;
                    W[q] = *(const f4*)&cur[rr * ZW_ + c0];
                }
#pragma unroll
                for (int i = 0; i < 5; ++i) {
                    const int row = rbase + i;
                    const int wr = (row + 4 < LROWS_) ? (row + 4) : (LROWS_ - 1);
                    W[8] = *(const f4*)&cur[wr * ZW_ + c0];
                    if (row >= L && row < R) {
                        const f4 lf = *(const f4*)&cur[row * ZW_ + c0 - 4];
                        const f4 rt = *(const f4*)&cur[row * ZW_ + c0 + 4];
                        const f4 pv = *(const f4*)&nxt[row * ZW_ + c0];
                        float xw[12];
#pragma unroll
                        for (int j = 0; j < 4; ++j) { xw[j] = lf[j]; xw[4 + j] = W[4][j]; xw[8 + j] = rt[j]; }
                        f4 res;
#pragma unroll
                        for (int j = 0; j < 4; ++j) {
                            const float ct = xw[4 + j];
                            float lap = 2.0f * (-205.0f / 72.0f) * ct;
                            lap += (8.0f / 5.0f)    * ((xw[j + 3] + xw[j + 5]) + (W[3][j] + W[5][j]));
                            lap += (-1.0f / 5.0f)   * ((xw[j + 2] + xw[j + 6]) + (W[2][j] + W[6][j]));
                            lap += (8.0f / 315.0f)  * ((xw[j + 1] + xw[j + 7]) + (W[1][j] + W[7][j]));
                            lap += (-1.0f / 560.0f) * ((xw[j + 0] + xw[j + 8]) + (W[0][j] + W[8][j]));
                            res[j] = 2.0f * ct - pv[j] + v2r[i][j] * lap;
                        }
                        if (zg != 37) {
                            *(f4*)&nxt[row * ZW_ + c0] = res;
                        } else {                               // z=148,149; keep pads zero
                            nxt[row * ZW_ + c0]     = res[0];
                            nxt[row * ZW_ + c0 + 1] = res[1];
                        }
                        if (row == srow && zg == szg)
                            nxt[row * ZW_ + scol] += sS * s_amp[s * NT_ + tau - 1];
                    }
#pragma unroll
                    for (int q = 0; q < 8; ++q) W[q] = W[q + 1];
                }
            }
            __syncthreads();
            if (rown) {
                const float* nb = smem + (tau & 1) * BUF_;
                out[((size_t)s * NT_ + (tau - 1)) * NR_ + tid] = nb[rrow * ZW_ + rcol];
            }

            // ---- early u(t+7)=buf1 exchange: publish+flagA now, ingest-issue,
            //      loads fly under k=8; committed to LDS at the transition ----
            if (k == 7 && r < NRND_ - 1) {
                const int par = r & 1;
                if (sideL && h > 0) {
                    u64* dst = halo + (size_t)(((s * NBND_ + h - 1) * 2 + 1) * 2 + par) * HELE_ + 2400;
                    for (int e = tidS; e < 2400; e += 256) {
                        const int row = e / 75, zp = e - row * 75;
                        astore64(dst + e, *(const u64*)&smem[BUF_ + (HW_ + row) * ZW_ + 4 + 2 * zp]);
                    }
                    asm volatile("s_waitcnt vmcnt(0)" ::: "memory");   // wave-scoped drain
                    if ((tid & 63) == 0) astore32(flagp(flagsA, s, h - 1, 1, wv), r + 1);
                } else if (sideR && h < NCH_ - 1) {
                    u64* dst = halo + (size_t)(((s * NBND_ + h) * 2 + 0) * 2 + par) * HELE_ + 2400;
                    for (int e = tidS; e < 2400; e += 256) {
                        const int row = e / 75, zp = e - row * 75;
                        astore64(dst + e, *(const u64*)&smem[BUF_ + (w + row) * ZW_ + 4 + 2 * zp]);
                    }
                    asm volatile("s_waitcnt vmcnt(0)" ::: "memory");
                    if ((tid & 63) == 0) astore32(flagp(flagsA, s, h, 0, wv), r + 1);
                }
                if (sideL && h > 0) {
                    const int* fp = flagp(flagsA, s, h - 1, 0, wv);
                    while (aload32(fp) <= r) __builtin_amdgcn_s_sleep(1);
                    const u64* src = halo + (size_t)(((s * NBND_ + h - 1) * 2 + 0) * 2 + par) * HELE_ + 2400;
#pragma unroll
                    for (int q = 0; q < NB_H; ++q) {
                        const int e = tidS + 256 * q;
                        ld2_issue(vb[q], src + (e < 2400 ? e : 2399));
                    }
                } else if (sideR && h < NCH_ - 1) {
                    const int* fp = flagp(flagsA, s, h, 1, wv);
                    while (aload32(fp) <= r) __builtin_amdgcn_s_sleep(1);
                    const u64* src = halo + (size_t)(((s * NBND_ + h) * 2 + 1) * 2 + par) * HELE_ + 2400;
#pragma unroll
                    for (int q = 0; q < NB_H; ++q) {
                        const int e = tidS + 256 * q;
                        ld2_issue(vb[q], src + (e < 2400 ? e : 2399));
                    }
                }
            }
        }

        if (r < NRND_ - 1) {
            const int par = r & 1;
            if (tid < 512) {
                // commit the in-flight u(t+7) halo regs to LDS
                asm volatile("s_waitcnt vmcnt(0)" ::: "memory");
                __builtin_amdgcn_sched_barrier(0);
                if (sideL && h > 0) {
#pragma unroll
                    for (int q = 0; q < NB_H; ++q) {
                        const int e = tidS + 256 * q;
                        if (e < 2400) {
                            const int row = e / 75, zp = e - row * 75;
                            *(u64*)&smem[BUF_ + row * ZW_ + 4 + 2 * zp] = vb[q];
                        }
                    }
                } else if (sideR && h < NCH_ - 1) {
#pragma unroll
                    for (int q = 0; q < NB_H; ++q) {
                        const int e = tidS + 256 * q;
                        if (e < 2400) {
                            const int row = e / 75, zp = e - row * 75;
                            *(u64*)&smem[BUF_ + (rhi + row) * ZW_ + 4 + 2 * zp] = vb[q];
                        }
                    }
                }
                // publish u(t+8)=buf0 slab, wave-granular drain + flagB
                if (sideL && h > 0) {
                    u64* dst = halo + (size_t)(((s * NBND_ + h - 1) * 2 + 1) * 2 + par) * HELE_;
                    for (int e = tidS; e < 2400; e += 256) {
                        const int row = e / 75, zp = e - row * 75;
                        astore64(dst + e, *(const u64*)&smem[(HW_ + row) * ZW_ + 4 + 2 * zp]);
                    }
                    asm volatile("s_waitcnt vmcnt(0)" ::: "memory");
                    if ((tid & 63) == 0) astore32(flagp(flagsB, s, h - 1, 1, wv), r + 1);
                } else if (sideR && h < NCH_ - 1) {
                    u64* dst = halo + (size_t)(((s * NBND_ + h) * 2 + 0) * 2 + par) * HELE_;
                    for (int e = tidS; e < 2400; e += 256) {
                        const int row = e / 75, zp = e - row * 75;
                        astore64(dst + e, *(const u64*)&smem[(w + row) * ZW_ + 4 + 2 * zp]);
                    }
                    asm volatile("s_waitcnt vmcnt(0)" ::: "memory");
                    if ((tid & 63) == 0) astore32(flagp(flagsB, s, h, 0, wv), r + 1);
                }
                // poll partner wave's flagB + batched ingest of u(t+8) halos
                if (sideL && h > 0) {
                    const int* fp = flagp(flagsB, s, h - 1, 0, wv);
                    while (aload32(fp) <= r) __builtin_amdgcn_s_sleep(1);
                    const u64* src = halo + (size_t)(((s * NBND_ + h - 1) * 2 + 0) * 2 + par) * HELE_;
#pragma unroll
                    for (int q = 0; q < NB_H; ++q) {
                        const int e = tidS + 256 * q;
                        ld2_issue(vb[q], src + (e < 2400 ? e : 2399));
                    }
                    asm volatile("s_waitcnt vmcnt(0)" ::: "memory");
                    __builtin_amdgcn_sched_barrier(0);
#pragma unroll
                    for (int q = 0; q < NB_H; ++q) {
                        const int e = tidS + 256 * q;
                        if (e < 2400) {
                            const int row = e / 75, zp = e - row * 75;
                            *(u64*)&smem[row * ZW_ + 4 + 2 * zp] = vb[q];
                        }
                    }
                } else if (sideR && h < NCH_ - 1) {
                    const int* fp = flagp(flagsB, s, h, 1, wv);
                    while (aload32(fp) <= r) __builtin_amdgcn_s_sleep(1);
                    const u64* src = halo + (size_t)(((s * NBND_ + h) * 2 + 1) * 2 + par) * HELE_;
#pragma unroll
                    for (int q = 0; q < NB_H; ++q) {
                        const int e = tidS + 256 * q;
                        ld2_issue(vb[q], src + (e < 2400 ? e : 2399));
                    }
                    asm volatile("s_waitcnt vmcnt(0)" ::: "memory");
                    __builtin_amdgcn_sched_barrier(0);
#pragma unroll
                    for (int q = 0; q < NB_H; ++q) {
                        const int e = tidS + 256 * q;
                        if (e < 2400) {
                            const int row = e / 75, zp = e - row * 75;
                            *(u64*)&smem[(rhi + row) * ZW_ + 4 + 2 * zp] = vb[q];
                        }
                    }
                }
            }
            __syncthreads();   // halos of both fields in place for next round
        }
    }
}

extern "C" void kernel_launch(void* const* d_in, const int* in_sizes, int n_in,
                              void* d_out, int out_size, void* d_ws, size_t ws_size,
                              hipStream_t stream) {
    const float* v_map = (const float*)d_in[0];
    const float* s_amp = (const float*)d_in[1];
    const int*   s_loc = (const int*)d_in[2];
    const int*   r_loc = (const int*)d_in[3];
    float* out = (float*)d_out;

    int* flagsA = (int*)d_ws;                       // 256 ints
    int* flagsB = (int*)((char*)d_ws + 1024);       // 256 ints
    u64* halo   = (u64*)((char*)d_ws + 4096);       // 4*8*2*2*4800*8 = 4.92 MB

    hipMemsetAsync(d_ws, 0, 4096, stream);          // reset both flag sets

    const int smem_bytes = 2 * BUF_ * 4;            // 131,712 B
    static bool attr_set = false;
    if (!attr_set) {                                // host-side, idempotent
        hipFuncSetAttribute((const void*)wave_ox,
                            hipFuncAttributeMaxDynamicSharedMemorySize, smem_bytes);
        attr_set = true;
    }

    wave_ox<<<dim3(NS_ * NCH_), dim3(THR_), smem_bytes, stream>>>(
        v_map, s_amp, s_loc, r_loc, out, flagsA, flagsB, halo);
}

// Round 12
// 3489.881 us; speedup vs baseline: 1.1085x; 1.1085x over previous
//
#include <hip/hip_runtime.h>

// 2D acoustic FD, 4 shots x 1000 steps. Temporal blocking K=8 with 18 x-chunks
// per shot (w=17/16 < halo 32): halos span TWO neighbor chunks, exchanged via a
// shared absolute-x strip buffer U[s][par][f][x][z]. Publishers write their
// whole interior; consumers poll 1-2 covering blocks per side and batch-ingest
// 32 cols/side (R6 protocol otherwise). 72 blocks. Compute body = R6.

#define NZ_ 150
#define NX_ 300
#define NT_ 1000
#define NS_ 4
#define NR_ 400
#define KS_ 8
#define NCH_ 18
#define HW_ 32               // halo width = 4*KS
#define ZW_ 168              // LDS z-stride
#define LROWS_ 81            // 32 + 17 + 32
#define BUF_ (LROWS_*ZW_)
#define THR_ 512
#define NRND_ 125
#define SLAB_ (300*75)       // u64 per (s,par,f) strip slab
#define NBATCH 19            // ceil(2*32*75/256)

typedef float f4 __attribute__((ext_vector_type(4)));
typedef unsigned long long u64;

__device__ __forceinline__ void astore64(u64* p, u64 v) {
    __hip_atomic_store(p, v, __ATOMIC_RELAXED, __HIP_MEMORY_SCOPE_AGENT);
}
__device__ __forceinline__ int aload32(const int* p) {
    return __hip_atomic_load(p, __ATOMIC_RELAXED, __HIP_MEMORY_SCOPE_AGENT);
}
__device__ __forceinline__ void astore32(int* p, int v) {
    __hip_atomic_store(p, v, __ATOMIC_RELAXED, __HIP_MEMORY_SCOPE_AGENT);
}
__device__ __forceinline__ void ld2_issue(u64& d, const u64* p) {
    asm volatile("global_load_dwordx2 %0, %1, off sc0 sc1" : "=v"(d) : "v"(p));
}
__device__ __forceinline__ int chunk_of(int x) {        // 12x17 + 6x16 = 300
    return x < 204 ? x / 17 : 12 + (x - 204) / 16;
}

__global__ __launch_bounds__(THR_) void wave_st(
    const float* __restrict__ v_map, const float* __restrict__ s_amp,
    const int* __restrict__ s_loc, const int* __restrict__ r_loc,
    float* __restrict__ out, int* __restrict__ flags, u64* __restrict__ strip)
{
    extern __shared__ float smem[];
    const int bi = blockIdx.x;
    const int s = bi & 3;
    const int h = bi >> 2;                       // 0..17
    const int tid = threadIdx.x;

    const int w  = (h < 12) ? 17 : 16;
    const int x0 = (h < 12) ? 17 * h : 204 + 16 * (h - 12);
    const int x1 = x0 + w;
    const int rhi = HW_ + w;

    for (int i = tid; i < 2 * BUF_; i += THR_) smem[i] = 0.0f;

    const int zg = tid % 38;                     // 4-wide z group (R6 banking)
    const int xp = tid / 38;                     // x-slice, 7 rows each
    const bool comp = (tid < 418);               // 38*11 slices cover rows 0..76
    const int c0 = 4 + 4 * zg;
    const int rbase = 7 * xp;

    f4 v2r[7];
#pragma unroll
    for (int i = 0; i < 7; ++i) {
        f4 vv = {0.f, 0.f, 0.f, 0.f};
        const int row = rbase + i;
        const int x = x0 - HW_ + row;
        if (comp && x >= 0 && x < NX_) {
#pragma unroll
            for (int j = 0; j < 4; ++j) {
                const int z = min(4 * zg + j, NZ_ - 1);
                const float v = v_map[z * NX_ + x] * 0.001f;
                vv[j] = v * v * 0.01f;           // (v*DT)^2 / DX^2
            }
        }
        v2r[i] = vv;
    }

    const int sz = s_loc[2 * s], sx = s_loc[2 * s + 1];
    float sS = v_map[sz * NX_ + sx] * 0.001f; sS = sS * sS;   // (v*DT)^2
    const int srow = sx - x0 + HW_;
    const int szg = sz >> 2;
    const int scol = 4 + sz;

    bool rown = false; int rrow = 0, rcol = 0;
    if (tid < NR_) {
        const int rz = r_loc[2 * tid];
        const int rx = r_loc[2 * tid + 1];
        if (rx >= x0 && rx < x1) { rown = true; rrow = HW_ + rx - x0; rcol = 4 + rz; }
    }

    const int nL = min(32, x0);                  // ingestible cols left of x0
    const int nR = min(32, NX_ - x1);            // right of x1
    const int gL = (h > 0) ? chunk_of(x0 - nL) : 0;
    const int gR = (h < NCH_ - 1) ? chunk_of(x1 + nR - 1) : 0;

    __syncthreads();

    for (int r = 0; r < NRND_; ++r) {
        for (int k = 1; k <= KS_; ++k) {
            const int tau = KS_ * r + k;
            const int ext = 4 * (KS_ - k);                     // 28..0
            const int L  = HW_ - min(ext, x0);                 // clamp at x=0 BC
            const int R  = rhi + min(ext, NX_ - x1);           // clamp at x=299 BC
            const float* cur = smem + ((tau + 1) & 1) * BUF_;
            float*       nxt = smem + (tau & 1) * BUF_;

            if (comp && rbase < R && rbase + 7 > L) {
                f4 W[9];
#pragma unroll
                for (int q = 0; q < 8; ++q) {
                    int rr = rbase - 4 + q; rr = rr < 0 ? 0 : rr;
                    W[q] = *(const f4*)&cur[rr * ZW_ + c0];
                }
#pragma unroll
                for (int i = 0; i < 7; ++i) {
                    const int row = rbase + i;
                    const int wr = (row + 4 < LROWS_) ? (row + 4) : (LROWS_ - 1);
                    W[8] = *(const f4*)&cur[wr * ZW_ + c0];
                    if (row >= L && row < R) {
                        const f4 lf = *(const f4*)&cur[row * ZW_ + c0 - 4];
                        const f4 rt = *(const f4*)&cur[row * ZW_ + c0 + 4];
                        const f4 pv = *(const f4*)&nxt[row * ZW_ + c0];
                        float xw[12];
#pragma unroll
                        for (int j = 0; j < 4; ++j) { xw[j] = lf[j]; xw[4 + j] = W[4][j]; xw[8 + j] = rt[j]; }
                        f4 res;
#pragma unroll
                        for (int j = 0; j < 4; ++j) {
                            const float ct = xw[4 + j];
                            float lap = 2.0f * (-205.0f / 72.0f) * ct;
                            lap += (8.0f / 5.0f)    * ((xw[j + 3] + xw[j + 5]) + (W[3][j] + W[5][j]));
                            lap += (-1.0f / 5.0f)   * ((xw[j + 2] + xw[j + 6]) + (W[2][j] + W[6][j]));
                            lap += (8.0f / 315.0f)  * ((xw[j + 1] + xw[j + 7]) + (W[1][j] + W[7][j]));
                            lap += (-1.0f / 560.0f) * ((xw[j + 0] + xw[j + 8]) + (W[0][j] + W[8][j]));
                            res[j] = 2.0f * ct - pv[j] + v2r[i][j] * lap;
                        }
                        if (zg != 37) {
                            *(f4*)&nxt[row * ZW_ + c0] = res;
                        } else {                               // z=148,149; keep pads zero
                            nxt[row * ZW_ + c0]     = res[0];
                            nxt[row * ZW_ + c0 + 1] = res[1];
                        }
                        if (row == srow && zg == szg)
                            nxt[row * ZW_ + scol] += sS * s_amp[s * NT_ + tau - 1];
                    }
#pragma unroll
                    for (int q = 0; q < 8; ++q) W[q] = W[q + 1];
                }
            }
            __syncthreads();
            if (rown) {
                const float* nb = smem + (tau & 1) * BUF_;
                out[((size_t)s * NT_ + (tau - 1)) * NR_ + tid] = nb[rrow * ZW_ + rcol];
            }
        }

        if (r < NRND_ - 1) {
            const int par = r & 1;
            u64* sp = strip + (size_t)((s * 2 + par) * 2) * SLAB_;   // +f*SLAB_
            // ---- publish whole interior (both fields) into the strip ----
            {
                const int w75 = w * 75, E2 = 2 * w75;
#pragma unroll
                for (int q = 0; q < 5; ++q) {
                    const int e = tid + 512 * q;
                    if (e < E2) {
                        const int f = (e >= w75);
                        const int rem = e - f * w75;
                        const int col = rem / 75, zp = rem - col * 75;
                        astore64(sp + (size_t)f * SLAB_ + (x0 + col) * 75 + zp,
                                 *(const u64*)&smem[f * BUF_ + (HW_ + col) * ZW_ + 4 + 2 * zp]);
                    }
                }
            }
            asm volatile("s_waitcnt vmcnt(0)" ::: "memory");   // per-wave drain
            __syncthreads();                                    // all waves drained
            if (tid == 0) astore32(&flags[s * NCH_ + h], r + 1);
            // ---- poll covering blocks (<=2/side), batched ingest 32 cols/side ----
            if (tid < 256) {
                if (h > 0 && nL > 0) {
                    for (int g = gL; g < h; ++g) {
                        const int* fp = &flags[s * NCH_ + g];
                        while (aload32(fp) <= r) __builtin_amdgcn_s_sleep(1);
                    }
                    const int n75 = nL * 75, E = 2 * n75;
                    u64 vb[NBATCH];
#pragma unroll
                    for (int q = 0; q < NBATCH; ++q) {
                        const int e = tid + 256 * q;
                        const int ec = (e < E) ? e : 0;
                        const int f = (ec >= n75);
                        const int rem = ec - f * n75;
                        const int col = rem / 75, zp = rem - col * 75;
                        ld2_issue(vb[q], sp + (size_t)f * SLAB_ + (x0 - nL + col) * 75 + zp);
                    }
                    asm volatile("s_waitcnt vmcnt(0)" ::: "memory");
                    __builtin_amdgcn_sched_barrier(0);
#pragma unroll
                    for (int q = 0; q < NBATCH; ++q) {
                        const int e = tid + 256 * q;
                        if (e < E) {
                            const int f = (e >= n75);
                            const int rem = e - f * n75;
                            const int col = rem / 75, zp = rem - col * 75;
                            *(u64*)&smem[f * BUF_ + (HW_ - nL + col) * ZW_ + 4 + 2 * zp] = vb[q];
                        }
                    }
                }
            } else {
                if (h < NCH_ - 1 && nR > 0) {
                    for (int g = h + 1; g <= gR; ++g) {
                        const int* fp = &flags[s * NCH_ + g];
                        while (aload32(fp) <= r) __builtin_amdgcn_s_sleep(1);
                    }
                    const int tidS = tid - 256;
                    const int n75 = nR * 75, E = 2 * n75;
                    u64 vb[NBATCH];
#pragma unroll
                    for (int q = 0; q < NBATCH; ++q) {
                        const int e = tidS + 256 * q;
                        const int ec = (e < E) ? e : 0;
                        const int f = (ec >= n75);
                        const int rem = ec - f * n75;
                        const int col = rem / 75, zp = rem - col * 75;
                        ld2_issue(vb[q], sp + (size_t)f * SLAB_ + (x1 + col) * 75 + zp);
                    }
                    asm volatile("s_waitcnt vmcnt(0)" ::: "memory");
                    __builtin_amdgcn_sched_barrier(0);
#pragma unroll
                    for (int q = 0; q < NBATCH; ++q) {
                        const int e = tidS + 256 * q;
                        if (e < E) {
                            const int f = (e >= n75);
                            const int rem = e - f * n75;
                            const int col = rem / 75, zp = rem - col * 75;
                            *(u64*)&smem[f * BUF_ + (rhi + col) * ZW_ + 4 + 2 * zp] = vb[q];
                        }
                    }
                }
            }
            __syncthreads();   // halos in place for next round
        }
    }
}

extern "C" void kernel_launch(void* const* d_in, const int* in_sizes, int n_in,
                              void* d_out, int out_size, void* d_ws, size_t ws_size,
                              hipStream_t stream) {
    const float* v_map = (const float*)d_in[0];
    const float* s_amp = (const float*)d_in[1];
    const int*   s_loc = (const int*)d_in[2];
    const int*   r_loc = (const int*)d_in[3];
    float* out = (float*)d_out;

    int* flags = (int*)d_ws;                        // 72 ints
    u64* strip = (u64*)((char*)d_ws + 1024);        // 16*300*75*8 = 2.88 MB

    hipMemsetAsync(d_ws, 0, 1024, stream);          // reset flags each call

    const int smem_bytes = 2 * BUF_ * 4;            // 108,864 B
    static bool attr_set = false;
    if (!attr_set) {                                // host-side, idempotent
        hipFuncSetAttribute((const void*)wave_st,
                            hipFuncAttributeMaxDynamicSharedMemorySize, smem_bytes);
        attr_set = true;
    }

    wave_st<<<dim3(NS_ * NCH_), dim3(THR_), smem_bytes, stream>>>(
        v_map, s_amp, s_loc, r_loc, out, flags, strip);
}

// Round 13
// 2812.454 us; speedup vs baseline: 1.3755x; 1.2409x over previous
//
#include <hip/hip_runtime.h>

// 2D acoustic FD, 4 shots x 1000 steps. Temporal blocking K=8:
// 9 x-chunks/shot (33-34 interior cols), full z in LDS (transposed layout),
// 32-col halos of {u(t+8),u(t+7)} exchanged every 8 steps via agent-scope
// protocol. Batched ingest (19 global_load_dwordx2 sc0 sc1 in flight, ONE
// vmcnt wait). == R6, the measured optimum (2826 us); R7-R12 variations
// (compute layout, pv-in-reg, overlap, wave-granular flags, 18-chunk
// decomposition) all regressed or were neutral. This is the final design.

#define NZ_ 150
#define NX_ 300
#define NT_ 1000
#define NS_ 4
#define NR_ 400
#define KS_ 8
#define NCH_ 9
#define NBND_ 8
#define HW_ 32               // halo width = 4*KS
#define ZW_ 168              // LDS z-stride (4 pad + 150 + 4 pad + align)
#define LROWS_ 98            // 32 + 34 + 32 max rows per chunk
#define BUF_ (LROWS_*ZW_)
#define THR_ 512
#define NRND_ 125
#define HELE_ 4800           // u64 per (s,bnd,dir,par): 2 fields*32 rows*75 zpairs
#define NBATCH 19            // ceil(4800/256)

typedef float f4 __attribute__((ext_vector_type(4)));
typedef unsigned long long u64;

__device__ __forceinline__ void astore64(u64* p, u64 v) {
    __hip_atomic_store(p, v, __ATOMIC_RELAXED, __HIP_MEMORY_SCOPE_AGENT);
}
__device__ __forceinline__ int aload32(const int* p) {
    return __hip_atomic_load(p, __ATOMIC_RELAXED, __HIP_MEMORY_SCOPE_AGENT);
}
__device__ __forceinline__ void astore32(int* p, int v) {
    __hip_atomic_store(p, v, __ATOMIC_RELAXED, __HIP_MEMORY_SCOPE_AGENT);
}
// batched ingest: issue without waiting; sc0 sc1 = bypass L1+L2, read MALL
__device__ __forceinline__ void ld2_issue(u64& d, const u64* p) {
    asm volatile("global_load_dwordx2 %0, %1, off sc0 sc1" : "=v"(d) : "v"(p));
}

__global__ __launch_bounds__(THR_) void wave_tb8b(
    const float* __restrict__ v_map, const float* __restrict__ s_amp,
    const int* __restrict__ s_loc, const int* __restrict__ r_loc,
    float* __restrict__ out, int* __restrict__ flags, u64* __restrict__ halo)
{
    extern __shared__ float smem[];
    const int bi = blockIdx.x;
    const int s = bi & 3;
    const int h = bi >> 2;                       // 0..8
    const int tid = threadIdx.x;

    const int w  = 33 + (h < 3 ? 1 : 0);
    const int x0 = 33 * h + (h < 3 ? h : 3);
    const int rhi = HW_ + w;

    for (int i = tid; i < 2 * BUF_; i += THR_) smem[i] = 0.0f;

    const int zg = tid % 38;                     // 4-wide z group
    const int xp = tid / 38;                     // x-slice, 8 rows each
    const bool comp = (tid < 494);               // 38*13
    const int c0 = 4 + 4 * zg;
    const int rbase = 8 * xp;

    f4 v2r[8];
#pragma unroll
    for (int i = 0; i < 8; ++i) {
        f4 vv = {0.f, 0.f, 0.f, 0.f};
        const int row = rbase + i;
        const int x = x0 - HW_ + row;
        if (comp && x >= 0 && x < NX_) {
#pragma unroll
            for (int j = 0; j < 4; ++j) {
                const int z = min(4 * zg + j, NZ_ - 1);
                const float v = v_map[z * NX_ + x] * 0.001f;
                vv[j] = v * v * 0.01f;           // (v*DT)^2 / DX^2
            }
        }
        v2r[i] = vv;
    }

    const int sz = s_loc[2 * s], sx = s_loc[2 * s + 1];
    float sS = v_map[sz * NX_ + sx] * 0.001f; sS = sS * sS;   // (v*DT)^2
    const int srow = sx - x0 + HW_;
    const int szg = sz >> 2;
    const int scol = 4 + sz;

    bool rown = false; int rrow = 0, rcol = 0;
    if (tid < NR_) {
        const int rz = r_loc[2 * tid];
        const int rx = r_loc[2 * tid + 1];
        if (rx >= x0 && rx < x0 + w) { rown = true; rrow = HW_ + rx - x0; rcol = 4 + rz; }
    }

    __syncthreads();

    for (int r = 0; r < NRND_; ++r) {
        for (int k = 1; k <= KS_; ++k) {
            const int tau = KS_ * r + k;
            const int ext = 4 * (KS_ - k);                     // 28..0
            const int L  = (h == 0)        ? HW_ : HW_ - ext;
            const int R  = (h == NCH_ - 1) ? rhi : rhi + ext;
            const float* cur = smem + ((tau + 1) & 1) * BUF_;
            float*       nxt = smem + (tau & 1) * BUF_;

            if (comp && rbase < R && rbase + 8 > L) {
                f4 W[9];
#pragma unroll
                for (int q = 0; q < 8; ++q) {
                    int rr = rbase - 4 + q; rr = rr < 0 ? 0 : rr;
                    W[q] = *(const f4*)&cur[rr * ZW_ + c0];
                }
#pragma unroll
                for (int i = 0; i < 8; ++i) {
                    const int row = rbase + i;
                    const int wr = (row + 4 < LROWS_) ? (row + 4) : (LROWS_ - 1);
                    W[8] = *(const f4*)&cur[wr * ZW_ + c0];
                    if (row >= L && row < R) {
                        const f4 lf = *(const f4*)&cur[row * ZW_ + c0 - 4];
                        const f4 rt = *(const f4*)&cur[row * ZW_ + c0 + 4];
                        const f4 pv = *(const f4*)&nxt[row * ZW_ + c0];
                        float xw[12];
#pragma unroll
                        for (int j = 0; j < 4; ++j) { xw[j] = lf[j]; xw[4 + j] = W[4][j]; xw[8 + j] = rt[j]; }
                        f4 res;
#pragma unroll
                        for (int j = 0; j < 4; ++j) {
                            const float ct = xw[4 + j];
                            float lap = 2.0f * (-205.0f / 72.0f) * ct;
                            lap += (8.0f / 5.0f)    * ((xw[j + 3] + xw[j + 5]) + (W[3][j] + W[5][j]));
                            lap += (-1.0f / 5.0f)   * ((xw[j + 2] + xw[j + 6]) + (W[2][j] + W[6][j]));
                            lap += (8.0f / 315.0f)  * ((xw[j + 1] + xw[j + 7]) + (W[1][j] + W[7][j]));
                            lap += (-1.0f / 560.0f) * ((xw[j + 0] + xw[j + 8]) + (W[0][j] + W[8][j]));
                            res[j] = 2.0f * ct - pv[j] + v2r[i][j] * lap;
                        }
                        if (zg != 37) {
                            *(f4*)&nxt[row * ZW_ + c0] = res;
                        } else {                               // z=148,149; keep pads zero
                            nxt[row * ZW_ + c0]     = res[0];
                            nxt[row * ZW_ + c0 + 1] = res[1];
                        }
                        if (row == srow && zg == szg)
                            nxt[row * ZW_ + scol] += sS * s_amp[s * NT_ + tau - 1];
                    }
#pragma unroll
                    for (int q = 0; q < 8; ++q) W[q] = W[q + 1];
                }
            }
            __syncthreads();
            if (rown) {
                const float* nb = smem + (tau & 1) * BUF_;
                out[((size_t)s * NT_ + (tau - 1)) * NR_ + tid] = nb[rrow * ZW_ + rcol];
            }
        }

        if (r < NRND_ - 1) {
            const int par = r & 1;
            // ---- publish 32 interior edge cols of u(t+8)=buf0, u(t+7)=buf1 ----
            if (tid < 256) {
                if (h > 0) {
                    u64* dst = halo + (size_t)(((s * NBND_ + h - 1) * 2 + 1) * 2 + par) * HELE_;
                    for (int e = tid; e < HELE_; e += 256) {
                        const int f = e / 2400, rem = e - f * 2400, row = rem / 75, zp = rem - row * 75;
                        astore64(dst + e, *(const u64*)&smem[f * BUF_ + (HW_ + row) * ZW_ + 4 + 2 * zp]);
                    }
                }
            } else {
                if (h < NCH_ - 1) {
                    u64* dst = halo + (size_t)(((s * NBND_ + h) * 2 + 0) * 2 + par) * HELE_;
                    for (int e = tid - 256; e < HELE_; e += 256) {
                        const int f = e / 2400, rem = e - f * 2400, row = rem / 75, zp = rem - row * 75;
                        astore64(dst + e, *(const u64*)&smem[f * BUF_ + (w + row) * ZW_ + 4 + 2 * zp]);
                    }
                }
            }
            asm volatile("s_waitcnt vmcnt(0)" ::: "memory");   // drain own publishes
            __syncthreads();
            if (tid == 0) {
                if (h > 0)
                    astore32(&flags[(s * NBND_ + h - 1) * 2 + 1], r + 1);
                if (h < NCH_ - 1)
                    astore32(&flags[(s * NBND_ + h) * 2 + 0], r + 1);
            }
            // ---- distributed poll, then BATCHED ingest (1 wait, not 19) ----
            if (tid < 256) {
                if (h > 0) {
                    const int* fp = &flags[(s * NBND_ + h - 1) * 2 + 0];
                    while (aload32(fp) <= r) __builtin_amdgcn_s_sleep(1);
                    const u64* src = halo + (size_t)(((s * NBND_ + h - 1) * 2 + 0) * 2 + par) * HELE_;
                    u64 vb[NBATCH];
#pragma unroll
                    for (int q = 0; q < NBATCH; ++q) {
                        const int e = tid + 256 * q;
                        ld2_issue(vb[q], src + (e < HELE_ ? e : HELE_ - 1));
                    }
                    asm volatile("s_waitcnt vmcnt(0)" ::: "memory");
                    __builtin_amdgcn_sched_barrier(0);
#pragma unroll
                    for (int q = 0; q < NBATCH; ++q) {
                        const int e = tid + 256 * q;
                        if (e < HELE_) {
                            const int f = e / 2400, rem = e - f * 2400, row = rem / 75, zp = rem - row * 75;
                            *(u64*)&smem[f * BUF_ + row * ZW_ + 4 + 2 * zp] = vb[q];
                        }
                    }
                }
            } else {
                if (h < NCH_ - 1) {
                    const int* fp = &flags[(s * NBND_ + h) * 2 + 1];
                    while (aload32(fp) <= r) __builtin_amdgcn_s_sleep(1);
                    const u64* src = halo + (size_t)(((s * NBND_ + h) * 2 + 1) * 2 + par) * HELE_;
                    u64 vb[NBATCH];
#pragma unroll
                    for (int q = 0; q < NBATCH; ++q) {
                        const int e = (tid - 256) + 256 * q;
                        ld2_issue(vb[q], src + (e < HELE_ ? e : HELE_ - 1));
                    }
                    asm volatile("s_waitcnt vmcnt(0)" ::: "memory");
                    __builtin_amdgcn_sched_barrier(0);
#pragma unroll
                    for (int q = 0; q < NBATCH; ++q) {
                        const int e = (tid - 256) + 256 * q;
                        if (e < HELE_) {
                            const int f = e / 2400, rem = e - f * 2400, row = rem / 75, zp = rem - row * 75;
                            *(u64*)&smem[f * BUF_ + (rhi + row) * ZW_ + 4 + 2 * zp] = vb[q];
                        }
                    }
                }
            }
            __syncthreads();
        }
    }
}

extern "C" void kernel_launch(void* const* d_in, const int* in_sizes, int n_in,
                              void* d_out, int out_size, void* d_ws, size_t ws_size,
                              hipStream_t stream) {
    const float* v_map = (const float*)d_in[0];
    const float* s_amp = (const float*)d_in[1];
    const int*   s_loc = (const int*)d_in[2];
    const int*   r_loc = (const int*)d_in[3];
    float* out = (float*)d_out;

    int* flags = (int*)d_ws;                        // 64 ints
    u64* halo  = (u64*)((char*)d_ws + 1024);        // 4*8*2*2*4800*8 = 4.92 MB

    hipMemsetAsync(d_ws, 0, 1024, stream);          // reset flags each call

    const int smem_bytes = 2 * BUF_ * 4;            // 131,712 B
    static bool attr_set = false;
    if (!attr_set) {                                // host-side, idempotent
        hipFuncSetAttribute((const void*)wave_tb8b,
                            hipFuncAttributeMaxDynamicSharedMemorySize, smem_bytes);
        attr_set = true;
    }

    wave_tb8b<<<dim3(NS_ * NCH_), dim3(THR_), smem_bytes, stream>>>(
        v_map, s_amp, s_loc, r_loc, out, flags, halo);
}